// Round 7
// baseline (285.177 us; speedup 1.0000x reference)
//
#include <hip/hip_runtime.h>
#include <stdint.h>

// DCT2D: y = Dh @ x @ Dw^T per (b,c); B=32,H=W=512,C=3, fp32 in/out.
// R7: (a) gemm1 was 1 block/CU (launch_bounds(512,2) let VGPR>128); now
// (512,4) + 32-bit address offsets to fit 128 VGPR -> 2 blocks/CU.
// (b) xpose rewritten: thread owns one jg column for 128 h -> 256 B
// contiguous stores (was 2x16B islands at 1KB stride = write amplification).
// GEMM structure unchanged from R6 (big tiles, BK=64, gload_lds + ^(row&7)
// chunk swizzle, simple 2-barrier loop).

typedef __bf16 bf16_t;
typedef bf16_t bf16x8 __attribute__((ext_vector_type(8)));
typedef float  f32x4  __attribute__((ext_vector_type(4)));

__device__ __forceinline__ uint32_t f2bf(float f) {
    union { float f; uint32_t u; } v; v.f = f;
    uint32_t r = v.u + 0x7fffu + ((v.u >> 16) & 1u);   // RNE
    return r >> 16;
}

__device__ __forceinline__ f32x4 mfma16(bf16x8 a, bf16x8 b, f32x4 c) {
    return __builtin_amdgcn_mfma_f32_16x16x32_bf16(a, b, c, 0, 0, 0);
}

__device__ __forceinline__ void load_lds16(const void* g, void* l) {
    __builtin_amdgcn_global_load_lds(
        (const __attribute__((address_space(1))) uint32_t*)g,
        (__attribute__((address_space(3))) uint32_t*)l, 16, 0, 0);
}

// ---------------- D matrix generation (bf16, row-major D[k][h]) -------------
__global__ __launch_bounds__(256) void gen_dct(uint16_t* __restrict__ Dbf) {
    int idx = blockIdx.x * 256 + threadIdx.x;      // 512*512 elems
    int k = idx >> 9, h = idx & 511;
    int phase = ((2 * h + 1) * k) & 2047;          // exact mod-2048 reduction
    float ang = (float)phase * 3.0679615757712823e-3f;   // pi/1024
    float s = (k == 0) ? 0.04419417382415922f : 0.0625f; // sqrt(1/512), sqrt(2/512)
    Dbf[idx] = (uint16_t)f2bf(__cosf(ang) * s);
}

// ---------------- xpose: x[b][h][w][c] fp32 -> Xt[b][jr][h] bf16 ------------
// jr = c*512 + wr, wr = (w>>8)*256 + ((w&255)>>1) + ((w&1)<<7)  (within-256
// even/odd pairing so G1's epilogue can store adjacent-w bf16 pairs as dwords).
// Each thread owns ONE raw column jg for 128 h: reads are wave-coalesced
// (64 consecutive floats per h-row), writes are 256 B contiguous per thread.
// Grid (6 jt, 4 hb, 32 b), 256 thr.
__global__ __launch_bounds__(256) void xpose(const float* __restrict__ x,
                                             uint16_t* __restrict__ Xt) {
    const int jt = blockIdx.x, hb = blockIdx.y, b = blockIdx.z;
    const int t = threadIdx.x;
    const int jg = jt * 256 + t;                   // raw col = w*3 + c
    const int w = jg / 3, c = jg - 3 * w;
    const int wr = ((w >> 8) << 8) + ((w & 255) >> 1) + ((w & 1) << 7);
    const int jr = c * 512 + wr;
    const float* src = x + (size_t)b * 786432 + (size_t)(hb * 128) * 1536 + jg;
    uint16_t* dst = Xt + ((size_t)b * 1536 + jr) * 512 + hb * 128;
#pragma unroll
    for (int hc = 0; hc < 4; ++hc) {
        float v[32];
#pragma unroll
        for (int r = 0; r < 32; ++r)
            v[r] = src[(size_t)(hc * 32 + r) * 1536];
        uint32_t p[16];
#pragma unroll
        for (int i = 0; i < 16; ++i)
            p[i] = f2bf(v[2 * i]) | (f2bf(v[2 * i + 1]) << 16);
#pragma unroll
        for (int u = 0; u < 4; ++u)
            *(uint4*)&dst[hc * 32 + u * 8] =
                make_uint4(p[4 * u], p[4 * u + 1], p[4 * u + 2], p[4 * u + 3]);
    }
}

// ---------------- G1: Y[b,k,c,w] = sum_h D[k,h] * x[b,h,(c,w)] --------------
// Per b: C[m=k(128-tile)][n=jr(256-tile)], K=h, BK=64, 8 iters.
// A = D rows, B = Xt rows, both via gload_lds with chunk^(row&7) src swizzle.
// 8 waves 2m x 4n; wave-tile 64k x 64j, n-frags at col-tiles wn+4f.
// launch_bounds(512,4): VGPR<=128 -> 2 blocks/CU (R7 fix; was 1).
__global__ __launch_bounds__(512, 4) void gemm1(const uint16_t* __restrict__ Xt,
                                                const uint16_t* __restrict__ Dbf,
                                                uint16_t* __restrict__ Y) {
    __shared__ __align__(16) uint16_t Al[128 * 64];   // 16 KB
    __shared__ __align__(16) uint16_t Bl[256 * 64];   // 32 KB
    const int t = threadIdx.x;
    const int lane = t & 63, wv = t >> 6;
    const int wm = wv >> 2, wn = wv & 3;
    const int nt = blockIdx.x;   // j-tile 0..5 (c = nt>>1, w-half = nt&1)
    const int mt = blockIdx.y;   // k-tile 0..3
    const int b  = blockIdx.z;

    // 32-bit source offsets (keeps VGPR under the (512,4) cap).
    const int qa0 = t, qa1 = t + 512;
    const int ma0 = qa0 >> 3, ga0 = (qa0 & 7) ^ (ma0 & 7);
    const int ma1 = qa1 >> 3, ga1 = (qa1 & 7) ^ (ma1 & 7);
    const uint32_t aoff0 = (uint32_t)(mt * 128 + ma0) * 512 + ga0 * 8;
    const uint32_t aoff1 = (uint32_t)(mt * 128 + ma1) * 512 + ga1 * 8;
    uint32_t boff[4];
#pragma unroll
    for (int i = 0; i < 4; ++i) {
        int q = t + 512 * i;
        int mb = q >> 3, gb = (q & 7) ^ (mb & 7);
        boff[i] = (uint32_t)(nt * 256 + mb) * 512 + gb * 8;
    }
    const uint16_t* Xb = Xt + (size_t)b * 786432;

    f32x4 acc[4][4] = {};   // [mf][f]

    for (int kt = 0; kt < 8; ++kt) {
        __syncthreads();
        load_lds16(Dbf + aoff0 + kt * 64, Al + qa0 * 8);
        load_lds16(Dbf + aoff1 + kt * 64, Al + qa1 * 8);
#pragma unroll
        for (int i = 0; i < 4; ++i)
            load_lds16(Xb + boff[i] + kt * 64, Bl + (t + 512 * i) * 8);
        __syncthreads();

#pragma unroll
        for (int ks = 0; ks < 2; ++ks) {
            bf16x8 aq[4], bq[4];
#pragma unroll
            for (int mf = 0; mf < 4; ++mf) {
                int row = wm * 64 + mf * 16 + (lane & 15);
                int sl = (ks * 4 + (lane >> 4)) ^ (row & 7);
                aq[mf] = *(const bf16x8*)&Al[row * 64 + sl * 8];
            }
#pragma unroll
            for (int f = 0; f < 4; ++f) {
                int col = (wn + 4 * f) * 16 + (lane & 15);
                int sl = (ks * 4 + (lane >> 4)) ^ (col & 7);
                bq[f] = *(const bf16x8*)&Bl[col * 64 + sl * 8];
            }
#pragma unroll
            for (int mf = 0; mf < 4; ++mf)
#pragma unroll
                for (int f = 0; f < 4; ++f)
                    acc[mf][f] = mfma16(aq[mf], bq[f], acc[mf][f]);
        }
    }

    // Epilogue: pair col-tiles (u, u+8) = (f, f+2) -> dword stores of two
    // bf16 at adjacent w. Y[b][k][c][w].
    const int cch = nt >> 1, whalf = nt & 1;
#pragma unroll
    for (int mf = 0; mf < 4; ++mf)
#pragma unroll
        for (int fp = 0; fp < 2; ++fp) {
            int kbase = mt * 128 + wm * 64 + mf * 16 + ((lane >> 4) << 2);
            int u = wn + 4 * fp;
            int w = whalf * 256 + 2 * (u * 16 + (lane & 15));
#pragma unroll
            for (int r = 0; r < 4; ++r) {
                uint32_t pk = f2bf(acc[mf][fp][r]) |
                              (f2bf(acc[mf][fp + 2][r]) << 16);
                *(uint32_t*)&Y[(size_t)b * 786432 + (size_t)(kbase + r) * 1536 +
                               cch * 512 + w] = pk;
            }
        }
}

// ---------------- G2: out[b,k,l,c] = sum_w D[l,w] * Y[b,k,c,w] --------------
// Per b: C[m=kc(96-tile)][n=l(256-tile)], K=w, BK=64, 8 iters.
// A = Y rows kc (w-contig), B = D rows l. 8 waves 2m x 4n; wave 48kc x 64l.
// Epilogue: 2 rounds (wm) of 48x257 fp32 LDS transpose -> coalesced float4.
__global__ __launch_bounds__(512, 4) void gemm2(const uint16_t* __restrict__ Y,
                                                const uint16_t* __restrict__ Dbf,
                                                float* __restrict__ out) {
    __shared__ __align__(16) char smem[49408];   // staging 45056 | El 49344
    uint16_t* Al = (uint16_t*)smem;              // 96*64 bf16 = 12288 B
    uint16_t* Bl = (uint16_t*)(smem + 12288);    // 256*64 bf16 = 32768 B
    float*    El = (float*)smem;                 // 48 x 257 fp32 epilogue
    const int t = threadIdx.x;
    const int lane = t & 63, wv = t >> 6;
    const int wm = wv >> 2, wn = wv & 3;
    const int mt = blockIdx.x;   // kc-tile 0..15
    const int lt = blockIdx.y;   // l-tile 0..1
    const int b  = blockIdx.z;
    const size_t yb = (size_t)b * 786432;

    const int qa0 = t, qa1 = t + 512;
    const int ma0 = qa0 >> 3, ga0 = (qa0 & 7) ^ (ma0 & 7);
    const int ma1 = qa1 >> 3, ga1 = (qa1 & 7) ^ (ma1 & 7);
    const uint32_t aoff0 = (uint32_t)(mt * 96 + ma0) * 512 + ga0 * 8;
    const uint32_t aoff1 = (uint32_t)(mt * 96 + ma1) * 512 + ga1 * 8;
    uint32_t boff[4];
#pragma unroll
    for (int i = 0; i < 4; ++i) {
        int q = t + 512 * i;
        int mb = q >> 3, gb = (q & 7) ^ (mb & 7);
        boff[i] = (uint32_t)(lt * 256 + mb) * 512 + gb * 8;
    }
    const uint16_t* Yb = Y + yb;

    f32x4 acc[3][4] = {};   // [mf][f]

    for (int kt = 0; kt < 8; ++kt) {
        __syncthreads();
        load_lds16(Yb + aoff0 + kt * 64, Al + qa0 * 8);
        if (t < 256) load_lds16(Yb + aoff1 + kt * 64, Al + qa1 * 8);
#pragma unroll
        for (int i = 0; i < 4; ++i)
            load_lds16(Dbf + boff[i] + kt * 64, Bl + (t + 512 * i) * 8);
        __syncthreads();

#pragma unroll
        for (int ks = 0; ks < 2; ++ks) {
            bf16x8 aq[3], bq[4];
#pragma unroll
            for (int mf = 0; mf < 3; ++mf) {
                int row = wm * 48 + mf * 16 + (lane & 15);
                int sl = (ks * 4 + (lane >> 4)) ^ (row & 7);
                aq[mf] = *(const bf16x8*)&Al[row * 64 + sl * 8];
            }
#pragma unroll
            for (int f = 0; f < 4; ++f) {
                int col = wn * 64 + f * 16 + (lane & 15);
                int sl = (ks * 4 + (lane >> 4)) ^ (col & 7);
                bq[f] = *(const bf16x8*)&Bl[col * 64 + sl * 8];
            }
#pragma unroll
            for (int mf = 0; mf < 3; ++mf)
#pragma unroll
                for (int f = 0; f < 4; ++f)
                    acc[mf][f] = mfma16(aq[mf], bq[f], acc[mf][f]);
        }
    }

    // Epilogue: rounds over wm-half (48 kc = 16 k x 3 c each). El pitch 257;
    // out stores contiguous float4: flat per k-row = k*1536 + lt*768 + z.
    const int kloc = t >> 5, zrow = t & 31;   // 16 k-rows, 32 thr/row
#pragma unroll
    for (int rnd = 0; rnd < 2; ++rnd) {
        __syncthreads();
        if (wm == rnd) {
#pragma unroll
            for (int mf = 0; mf < 3; ++mf)
#pragma unroll
                for (int f = 0; f < 4; ++f) {
                    int row = mf * 16 + ((lane >> 4) << 2);
                    int col = wn * 64 + f * 16 + (lane & 15);
#pragma unroll
                    for (int r = 0; r < 4; ++r)
                        El[(row + r) * 257 + col] = acc[mf][f][r];
                }
        }
        __syncthreads();
        int kbase = mt * 32 + rnd * 16;
        size_t ob = (size_t)b * 786432 + (size_t)(kbase + kloc) * 1536 + lt * 768;
#pragma unroll
        for (int q4 = 0; q4 < 6; ++q4) {
            int z0 = zrow * 24 + q4 * 4;
            float4 v;
            v.x = El[(kloc * 3 + ((z0 + 0) % 3)) * 257 + (z0 + 0) / 3];
            v.y = El[(kloc * 3 + ((z0 + 1) % 3)) * 257 + (z0 + 1) / 3];
            v.z = El[(kloc * 3 + ((z0 + 2) % 3)) * 257 + (z0 + 2) / 3];
            v.w = El[(kloc * 3 + ((z0 + 3) % 3)) * 257 + (z0 + 3) / 3];
            *(float4*)&out[ob + z0] = v;
        }
    }
}

// ---------------------------------------------------------------------------
extern "C" void kernel_launch(void* const* d_in, const int* in_sizes, int n_in,
                              void* d_out, int out_size, void* d_ws, size_t ws_size,
                              hipStream_t stream) {
    (void)in_sizes; (void)n_in; (void)out_size;
    const float* x = (const float*)d_in[0];
    float* out = (float*)d_out;
    uint16_t* Dbf = (uint16_t*)d_ws;                 // 512*512 bf16 = 512 KB
    uint16_t* Yw  = (uint16_t*)d_ws + 512 * 512;     // 32*512*512*3 bf16 = 48 MB
    size_t need = (size_t)512 * 512 * 2 + (size_t)2 * 32 * 1536 * 512 * 2;
    uint16_t* Xt = (ws_size >= need)
                     ? (uint16_t*)d_ws + 512 * 512 + (size_t)32 * 1536 * 512
                     : (uint16_t*)d_out;

    gen_dct<<<1024, 256, 0, stream>>>(Dbf);
    dim3 gt(6, 4, 32);
    xpose<<<gt, 256, 0, stream>>>(x, Xt);
    dim3 g1(6, 4, 32);
    gemm1<<<g1, 512, 0, stream>>>(Xt, Dbf, Yw);
    dim3 g2(16, 2, 32);
    gemm2<<<g2, 512, 0, stream>>>(Yw, Dbf, out);
}

// Round 8
// 267.399 us; speedup vs baseline: 1.0665x; 1.0665x over previous
//
#include <hip/hip_runtime.h>
#include <stdint.h>

// DCT2D: y = Dh @ x @ Dw^T per (b,c); B=32,H=W=512,C=3, fp32 in/out.
// R8: xpose rewritten as LDS transpose. R7's version had per-THREAD
// contiguous stores but per-INSTRUCTION 1KB-strided lanes (64 cache lines
// per store instr, WRITE_SIZE 67MB for 48MB logical). Now: read phase
// lane=jg (coalesced 256B loads), padded-LDS staging (pitch 130 u32,
// 2-way banks = free), write phase lane=h (contiguous 512B stores).
// gen/gemm1/gemm2 unchanged from R7.

typedef __bf16 bf16_t;
typedef bf16_t bf16x8 __attribute__((ext_vector_type(8)));
typedef float  f32x4  __attribute__((ext_vector_type(4)));

__device__ __forceinline__ uint32_t f2bf(float f) {
    union { float f; uint32_t u; } v; v.f = f;
    uint32_t r = v.u + 0x7fffu + ((v.u >> 16) & 1u);   // RNE
    return r >> 16;
}

__device__ __forceinline__ f32x4 mfma16(bf16x8 a, bf16x8 b, f32x4 c) {
    return __builtin_amdgcn_mfma_f32_16x16x32_bf16(a, b, c, 0, 0, 0);
}

__device__ __forceinline__ void load_lds16(const void* g, void* l) {
    __builtin_amdgcn_global_load_lds(
        (const __attribute__((address_space(1))) uint32_t*)g,
        (__attribute__((address_space(3))) uint32_t*)l, 16, 0, 0);
}

// ---------------- D matrix generation (bf16, row-major D[k][h]) -------------
__global__ __launch_bounds__(256) void gen_dct(uint16_t* __restrict__ Dbf) {
    int idx = blockIdx.x * 256 + threadIdx.x;      // 512*512 elems
    int k = idx >> 9, h = idx & 511;
    int phase = ((2 * h + 1) * k) & 2047;          // exact mod-2048 reduction
    float ang = (float)phase * 3.0679615757712823e-3f;   // pi/1024
    float s = (k == 0) ? 0.04419417382415922f : 0.0625f; // sqrt(1/512), sqrt(2/512)
    Dbf[idx] = (uint16_t)f2bf(__cosf(ang) * s);
}

// ---------------- xpose: x[b][h][w][c] fp32 -> Xt[b][jr][h] bf16 ------------
// jr = c*512 + wr, wr = (w>>8)*256 + ((w&255)>>1) + ((w&1)<<7)  (within-256
// even/odd pairing for G1's paired bf16 epilogue stores).
// Tile 64 jg x 256 h per block, LDS-staged:
//   read:  lane=jg -> 64x4B coalesced loads; pack h-pairs -> T[jg][h2]
//          (pitch 130 u32: bank=(2*jg+h2)%32, 2-way = free)
//   write: wave owns a jr row; lane spans h -> uint2/lane, 512B contiguous.
// Grid (24 jt, 2 hb, 32 b), 256 thr.
__global__ __launch_bounds__(256) void xpose(const float* __restrict__ x,
                                             uint16_t* __restrict__ Xt) {
    __shared__ uint32_t T[64 * 130];               // 33.3 KB
    const int jt = blockIdx.x, hb = blockIdx.y, b = blockIdx.z;
    const int t = threadIdx.x;
    const int lane = t & 63, wv = t >> 6;
    const int jg = jt * 64 + lane;
    const float* src = x + (size_t)b * 786432 +
                       (size_t)(hb * 256 + wv * 64) * 1536 + jg;
#pragma unroll
    for (int r = 0; r < 32; ++r) {
        float a = src[(size_t)(2 * r) * 1536];
        float c = src[(size_t)(2 * r + 1) * 1536];
        T[lane * 130 + wv * 32 + r] = f2bf(a) | (f2bf(c) << 16);
    }
    __syncthreads();
#pragma unroll
    for (int i = 0; i < 16; ++i) {
        int row = wv * 16 + i;
        int jg2 = jt * 64 + row;
        int w = jg2 / 3, c = jg2 - 3 * w;
        int wr = ((w >> 8) << 8) + ((w & 255) >> 1) + ((w & 1) << 7);
        int jr = c * 512 + wr;
        uint2 v = *(const uint2*)&T[row * 130 + 2 * lane];
        *(uint2*)&Xt[((size_t)b * 1536 + jr) * 512 + hb * 256 + 4 * lane] = v;
    }
}

// ---------------- G1: Y[b,k,c,w] = sum_h D[k,h] * x[b,h,(c,w)] --------------
// Per b: C[m=k(128-tile)][n=jr(256-tile)], K=h, BK=64, 8 iters.
// A = D rows, B = Xt rows, both via gload_lds with chunk^(row&7) src swizzle.
// 8 waves 2m x 4n; wave-tile 64k x 64j, n-frags at col-tiles wn+4f.
// launch_bounds(512,4): VGPR<=128 -> 2 blocks/CU.
__global__ __launch_bounds__(512, 4) void gemm1(const uint16_t* __restrict__ Xt,
                                                const uint16_t* __restrict__ Dbf,
                                                uint16_t* __restrict__ Y) {
    __shared__ __align__(16) uint16_t Al[128 * 64];   // 16 KB
    __shared__ __align__(16) uint16_t Bl[256 * 64];   // 32 KB
    const int t = threadIdx.x;
    const int lane = t & 63, wv = t >> 6;
    const int wm = wv >> 2, wn = wv & 3;
    const int nt = blockIdx.x;   // j-tile 0..5 (c = nt>>1, w-half = nt&1)
    const int mt = blockIdx.y;   // k-tile 0..3
    const int b  = blockIdx.z;

    // 32-bit source offsets (keeps VGPR under the (512,4) cap).
    const int qa0 = t, qa1 = t + 512;
    const int ma0 = qa0 >> 3, ga0 = (qa0 & 7) ^ (ma0 & 7);
    const int ma1 = qa1 >> 3, ga1 = (qa1 & 7) ^ (ma1 & 7);
    const uint32_t aoff0 = (uint32_t)(mt * 128 + ma0) * 512 + ga0 * 8;
    const uint32_t aoff1 = (uint32_t)(mt * 128 + ma1) * 512 + ga1 * 8;
    uint32_t boff[4];
#pragma unroll
    for (int i = 0; i < 4; ++i) {
        int q = t + 512 * i;
        int mb = q >> 3, gb = (q & 7) ^ (mb & 7);
        boff[i] = (uint32_t)(nt * 256 + mb) * 512 + gb * 8;
    }
    const uint16_t* Xb = Xt + (size_t)b * 786432;

    f32x4 acc[4][4] = {};   // [mf][f]

    for (int kt = 0; kt < 8; ++kt) {
        __syncthreads();
        load_lds16(Dbf + aoff0 + kt * 64, Al + qa0 * 8);
        load_lds16(Dbf + aoff1 + kt * 64, Al + qa1 * 8);
#pragma unroll
        for (int i = 0; i < 4; ++i)
            load_lds16(Xb + boff[i] + kt * 64, Bl + (t + 512 * i) * 8);
        __syncthreads();

#pragma unroll
        for (int ks = 0; ks < 2; ++ks) {
            bf16x8 aq[4], bq[4];
#pragma unroll
            for (int mf = 0; mf < 4; ++mf) {
                int row = wm * 64 + mf * 16 + (lane & 15);
                int sl = (ks * 4 + (lane >> 4)) ^ (row & 7);
                aq[mf] = *(const bf16x8*)&Al[row * 64 + sl * 8];
            }
#pragma unroll
            for (int f = 0; f < 4; ++f) {
                int col = (wn + 4 * f) * 16 + (lane & 15);
                int sl = (ks * 4 + (lane >> 4)) ^ (col & 7);
                bq[f] = *(const bf16x8*)&Bl[col * 64 + sl * 8];
            }
#pragma unroll
            for (int mf = 0; mf < 4; ++mf)
#pragma unroll
                for (int f = 0; f < 4; ++f)
                    acc[mf][f] = mfma16(aq[mf], bq[f], acc[mf][f]);
        }
    }

    // Epilogue: pair col-tiles (u, u+8) = (f, f+2) -> dword stores of two
    // bf16 at adjacent w. Y[b][k][c][w].
    const int cch = nt >> 1, whalf = nt & 1;
#pragma unroll
    for (int mf = 0; mf < 4; ++mf)
#pragma unroll
        for (int fp = 0; fp < 2; ++fp) {
            int kbase = mt * 128 + wm * 64 + mf * 16 + ((lane >> 4) << 2);
            int u = wn + 4 * fp;
            int w = whalf * 256 + 2 * (u * 16 + (lane & 15));
#pragma unroll
            for (int r = 0; r < 4; ++r) {
                uint32_t pk = f2bf(acc[mf][fp][r]) |
                              (f2bf(acc[mf][fp + 2][r]) << 16);
                *(uint32_t*)&Y[(size_t)b * 786432 + (size_t)(kbase + r) * 1536 +
                               cch * 512 + w] = pk;
            }
        }
}

// ---------------- G2: out[b,k,l,c] = sum_w D[l,w] * Y[b,k,c,w] --------------
// Per b: C[m=kc(96-tile)][n=l(256-tile)], K=w, BK=64, 8 iters.
// A = Y rows kc (w-contig), B = D rows l. 8 waves 2m x 4n; wave 48kc x 64l.
// Epilogue: 2 rounds (wm) of 48x257 fp32 LDS transpose -> coalesced float4.
__global__ __launch_bounds__(512, 4) void gemm2(const uint16_t* __restrict__ Y,
                                                const uint16_t* __restrict__ Dbf,
                                                float* __restrict__ out) {
    __shared__ __align__(16) char smem[49408];   // staging 45056 | El 49344
    uint16_t* Al = (uint16_t*)smem;              // 96*64 bf16 = 12288 B
    uint16_t* Bl = (uint16_t*)(smem + 12288);    // 256*64 bf16 = 32768 B
    float*    El = (float*)smem;                 // 48 x 257 fp32 epilogue
    const int t = threadIdx.x;
    const int lane = t & 63, wv = t >> 6;
    const int wm = wv >> 2, wn = wv & 3;
    const int mt = blockIdx.x;   // kc-tile 0..15
    const int lt = blockIdx.y;   // l-tile 0..1
    const int b  = blockIdx.z;
    const size_t yb = (size_t)b * 786432;

    const int qa0 = t, qa1 = t + 512;
    const int ma0 = qa0 >> 3, ga0 = (qa0 & 7) ^ (ma0 & 7);
    const int ma1 = qa1 >> 3, ga1 = (qa1 & 7) ^ (ma1 & 7);
    const uint32_t aoff0 = (uint32_t)(mt * 96 + ma0) * 512 + ga0 * 8;
    const uint32_t aoff1 = (uint32_t)(mt * 96 + ma1) * 512 + ga1 * 8;
    uint32_t boff[4];
#pragma unroll
    for (int i = 0; i < 4; ++i) {
        int q = t + 512 * i;
        int mb = q >> 3, gb = (q & 7) ^ (mb & 7);
        boff[i] = (uint32_t)(lt * 256 + mb) * 512 + gb * 8;
    }
    const uint16_t* Yb = Y + yb;

    f32x4 acc[3][4] = {};   // [mf][f]

    for (int kt = 0; kt < 8; ++kt) {
        __syncthreads();
        load_lds16(Yb + aoff0 + kt * 64, Al + qa0 * 8);
        if (t < 256) load_lds16(Yb + aoff1 + kt * 64, Al + qa1 * 8);
#pragma unroll
        for (int i = 0; i < 4; ++i)
            load_lds16(Dbf + boff[i] + kt * 64, Bl + (t + 512 * i) * 8);
        __syncthreads();

#pragma unroll
        for (int ks = 0; ks < 2; ++ks) {
            bf16x8 aq[3], bq[4];
#pragma unroll
            for (int mf = 0; mf < 3; ++mf) {
                int row = wm * 48 + mf * 16 + (lane & 15);
                int sl = (ks * 4 + (lane >> 4)) ^ (row & 7);
                aq[mf] = *(const bf16x8*)&Al[row * 64 + sl * 8];
            }
#pragma unroll
            for (int f = 0; f < 4; ++f) {
                int col = wn * 64 + f * 16 + (lane & 15);
                int sl = (ks * 4 + (lane >> 4)) ^ (col & 7);
                bq[f] = *(const bf16x8*)&Bl[col * 64 + sl * 8];
            }
#pragma unroll
            for (int mf = 0; mf < 3; ++mf)
#pragma unroll
                for (int f = 0; f < 4; ++f)
                    acc[mf][f] = mfma16(aq[mf], bq[f], acc[mf][f]);
        }
    }

    // Epilogue: rounds over wm-half (48 kc = 16 k x 3 c each). El pitch 257;
    // out stores contiguous float4: flat per k-row = k*1536 + lt*768 + z.
    const int kloc = t >> 5, zrow = t & 31;   // 16 k-rows, 32 thr/row
#pragma unroll
    for (int rnd = 0; rnd < 2; ++rnd) {
        __syncthreads();
        if (wm == rnd) {
#pragma unroll
            for (int mf = 0; mf < 3; ++mf)
#pragma unroll
                for (int f = 0; f < 4; ++f) {
                    int row = mf * 16 + ((lane >> 4) << 2);
                    int col = wn * 64 + f * 16 + (lane & 15);
#pragma unroll
                    for (int r = 0; r < 4; ++r)
                        El[(row + r) * 257 + col] = acc[mf][f][r];
                }
        }
        __syncthreads();
        int kbase = mt * 32 + rnd * 16;
        size_t ob = (size_t)b * 786432 + (size_t)(kbase + kloc) * 1536 + lt * 768;
#pragma unroll
        for (int q4 = 0; q4 < 6; ++q4) {
            int z0 = zrow * 24 + q4 * 4;
            float4 v;
            v.x = El[(kloc * 3 + ((z0 + 0) % 3)) * 257 + (z0 + 0) / 3];
            v.y = El[(kloc * 3 + ((z0 + 1) % 3)) * 257 + (z0 + 1) / 3];
            v.z = El[(kloc * 3 + ((z0 + 2) % 3)) * 257 + (z0 + 2) / 3];
            v.w = El[(kloc * 3 + ((z0 + 3) % 3)) * 257 + (z0 + 3) / 3];
            *(float4*)&out[ob + z0] = v;
        }
    }
}

// ---------------------------------------------------------------------------
extern "C" void kernel_launch(void* const* d_in, const int* in_sizes, int n_in,
                              void* d_out, int out_size, void* d_ws, size_t ws_size,
                              hipStream_t stream) {
    (void)in_sizes; (void)n_in; (void)out_size;
    const float* x = (const float*)d_in[0];
    float* out = (float*)d_out;
    uint16_t* Dbf = (uint16_t*)d_ws;                 // 512*512 bf16 = 512 KB
    uint16_t* Yw  = (uint16_t*)d_ws + 512 * 512;     // 32*512*512*3 bf16 = 48 MB
    size_t need = (size_t)512 * 512 * 2 + (size_t)2 * 32 * 1536 * 512 * 2;
    uint16_t* Xt = (ws_size >= need)
                     ? (uint16_t*)d_ws + 512 * 512 + (size_t)32 * 1536 * 512
                     : (uint16_t*)d_out;

    gen_dct<<<1024, 256, 0, stream>>>(Dbf);
    dim3 gt(24, 2, 32);
    xpose<<<gt, 256, 0, stream>>>(x, Xt);
    dim3 g1(6, 4, 32);
    gemm1<<<g1, 512, 0, stream>>>(Xt, Dbf, Yw);
    dim3 g2(16, 2, 32);
    gemm2<<<g2, 512, 0, stream>>>(Yw, Dbf, out);
}